// Round 1
// 71.609 us; speedup vs baseline: 1.0225x; 1.0225x over previous
//
#include <hip/hip_runtime.h>
#include <math.h>

#define PNUM 512
#define IMW 256
#define IMH 256
#define NCH 8      // waves per block (raster)
#define SEGW 64    // pixels per block (one 64-wide row segment)

// Two-kernel pipeline through d_ws (stream-ordered):
//   gr_prep   : 1 block, 512 threads. Full per-gaussian preprocess ONCE.
//               Writes 3x float4 per gaussian to ws + aux outputs (radii, viewspace).
//   gr_raster : 1024 blocks (one 64-px row segment each). Loads precomputed
//               params (48 B/thread, L2-resident), exact-safe cull, ballot-compact,
//               O(L^2) local rank-sort by (tz,idx), 8-wave chunked composite.
// This removes the 1024x-redundant preprocessing (~500 VALU instr/thread incl.
// ~10 precise divisions) that dominated the fused kernel's instruction count.

__global__ __launch_bounds__(512) void gr_prep(
    const float* __restrict__ points, const float* __restrict__ scales,
    const float* __restrict__ rots, const float* __restrict__ opac_in,
    const float* __restrict__ shs, const float* __restrict__ vm,
    float4* __restrict__ gp, float* __restrict__ out)
{
    const int i = threadIdx.x;

    const float px = points[3*i], py = points[3*i+1], pz = points[3*i+2];
    const float sx = __expf(scales[3*i]), sy = __expf(scales[3*i+1]), sz = __expf(scales[3*i+2]);
    const float op0 = 1.0f / (1.0f + __expf(-opac_in[i]));
    const float q0 = rots[4*i], q1 = rots[4*i+1], q2 = rots[4*i+2], q3 = rots[4*i+3];
    const float qinv = 1.0f / sqrtf(q0*q0 + q1*q1 + q2*q2 + q3*q3);
    const float r = q0*qinv, x = q1*qinv, y = q2*qinv, z = q3*qinv;

    const float R00 = 1.f - 2.f*(y*y + z*z);
    const float R01 = 2.f*(x*y - r*z);
    const float R02 = 2.f*(x*z + r*y);
    const float R10 = 2.f*(x*y + r*z);
    const float R11 = 1.f - 2.f*(x*x + z*z);
    const float R12 = 2.f*(y*z - r*x);
    const float R20 = 2.f*(x*z - r*y);
    const float R21 = 2.f*(y*z + r*x);
    const float R22 = 1.f - 2.f*(x*x + y*y);

    const float M00=R00*sx, M01=R01*sy, M02=R02*sz;
    const float M10=R10*sx, M11=R11*sy, M12=R12*sz;
    const float M20=R20*sx, M21=R21*sy, M22=R22*sz;

    const float S00 = M00*M00 + M01*M01 + M02*M02;
    const float S01 = M00*M10 + M01*M11 + M02*M12;
    const float S02 = M00*M20 + M01*M21 + M02*M22;
    const float S11 = M10*M10 + M11*M11 + M12*M12;
    const float S12 = M10*M20 + M11*M21 + M12*M22;
    const float S22 = M20*M20 + M21*M21 + M22*M22;

    const float W00=vm[0], W01=vm[1], W02=vm[2],  T0=vm[3];
    const float W10=vm[4], W11=vm[5], W12=vm[6],  T1=vm[7];
    const float W20=vm[8], W21=vm[9], W22=vm[10], T2=vm[11];
    const float tx = W00*px + W01*py + W02*pz + T0;
    const float ty = W10*px + W11*py + W12*pz + T1;
    const float tz = W20*px + W21*py + W22*pz + T2;

    bool vis = tz > 0.2f;
    const float tzs = vis ? tz : 1.0f;
    const float lim = 1.3f * 0.5f;
    const float txtz = fminf(fmaxf(tx / tzs, -lim), lim) * tzs;
    const float tytz = fminf(fmaxf(ty / tzs, -lim), lim) * tzs;

    const float FX = 256.0f, FY = 256.0f;
    const float J00 = FX / tzs;
    const float J02 = -FX * txtz / (tzs * tzs);
    const float J11 = FY / tzs;
    const float J12 = -FY * tytz / (tzs * tzs);

    const float Tm00 = J00*W00 + J02*W20;
    const float Tm01 = J00*W01 + J02*W21;
    const float Tm02 = J00*W02 + J02*W22;
    const float Tm10 = J11*W10 + J12*W20;
    const float Tm11 = J11*W11 + J12*W21;
    const float Tm12 = J11*W12 + J12*W22;

    const float U00 = Tm00*S00 + Tm01*S01 + Tm02*S02;
    const float U01 = Tm00*S01 + Tm01*S11 + Tm02*S12;
    const float U02 = Tm00*S02 + Tm01*S12 + Tm02*S22;
    const float U10 = Tm10*S00 + Tm11*S01 + Tm12*S02;
    const float U11 = Tm10*S01 + Tm11*S11 + Tm12*S12;
    const float U12 = Tm10*S02 + Tm11*S12 + Tm12*S22;

    const float cov00 = U00*Tm00 + U01*Tm01 + U02*Tm02;
    const float cov01 = U00*Tm10 + U01*Tm11 + U02*Tm12;
    const float cov11 = U10*Tm10 + U11*Tm11 + U12*Tm12;

    const float det_orig = cov00*cov11 - cov01*cov01;
    const float a = cov00 + 0.3f, c = cov11 + 0.3f, b = cov01;
    const float det = a*c - b*b;
    vis = vis && (det > 0.f);
    const float dets = (det > 0.f) ? det : 1.0f;
    const float compn = sqrtf(fmaxf(det_orig / dets, 0.f));
    const float op = vis ? op0 * compn : 0.f;
    const float invdet = 1.0f / dets;
    const float A2 = -0.5f * c * invdet;   // -0.5*conA
    const float B2 = b * invdet;           // -conB
    const float C2 = -0.5f * a * invdet;   // -0.5*conC

    const float mid = 0.5f * (a + c);
    const float lam = mid + sqrtf(fmaxf(mid*mid - det, 0.1f));

    const float mx = FX * tx / tzs + (IMW - 1) * 0.5f;
    const float my = FY * ty / tzs + (IMH - 1) * 0.5f;

    const float SH_C0 = 0.28209479177387814f;
    const float cr = fmaxf(shs[3*i  ] * SH_C0 + 0.5f, 0.f);
    const float cg = fmaxf(shs[3*i+1] * SH_C0 + 0.5f, 0.f);
    const float cb = fmaxf(shs[3*i+2] * SH_C0 + 0.5f, 0.f);

    // alpha >= 1/255 requires |d|^2 <= 2*lam*ln(255*op) (lam >= lambda_max)
    float rc2 = -1.f;
    const float p255 = 255.f * op;
    if (p255 > 1.f) rc2 = 2.f * lam * __logf(p255) * 1.001f + 0.01f;

    gp[i]          = make_float4(mx, my, rc2, tz);
    gp[PNUM + i]   = make_float4(A2, B2, C2, op);
    gp[2*PNUM + i] = make_float4(cr, cg, cb, 0.f);

    // aux outputs
    const float radii = vis ? ceilf(3.f * sqrtf(lam)) : 0.f;
    out[196608 + 3*i + 0] = 0.f;
    out[196608 + 3*i + 1] = 0.f;
    out[196608 + 3*i + 2] = 0.f;
    out[198144 + i] = radii;
}

__global__ __launch_bounds__(512, 4) void gr_raster(
    const float4* __restrict__ gp, float* __restrict__ out)
{
    __shared__ float k_tz[PNUM];
    __shared__ int   k_id[PNUM];
    __shared__ float smx[PNUM], smy[PNUM], sA[PNUM], sB[PNUM], sC[PNUM];
    __shared__ float sop[PNUM], scr[PNUM], scg[PNUM], scb[PNUM];
    __shared__ float pr[NCH*SEGW], pg[NCH*SEGW], pb[NCH*SEGW], pt[NCH*SEGW];
    __shared__ int scnt[NCH];

    const int tid  = threadIdx.x;      // gaussian id in cull/compact phases
    const int lane = tid & 63;
    const int wv   = tid >> 6;
    const int seg  = blockIdx.x;
    const int row  = seg >> 2;
    const int x0   = (seg & 3) << 6;
    const float fy = (float)row;

    // ---- load precomputed params (coalesced, L2/L1-resident: 24 KB total) ----
    const float4 g0 = gp[tid];            // mx, my, rc2, tz
    const float4 g1 = gp[PNUM + tid];     // A2, B2, C2, op
    const float4 g2 = gp[2*PNUM + tid];   // cr, cg, cb, -
    const float mx = g0.x, my = g0.y, rc2 = g0.z, tz = g0.w;

    // ---- exact-safe cull vs this segment ----
    const float dxl = (float)x0 - mx;
    const float dxr = mx - (float)(x0 + SEGW - 1);
    const float dxm = fmaxf(0.f, fmaxf(dxl, dxr));
    const float dym = fabsf(fy - my);
    const bool hit = (dxm*dxm + dym*dym) <= rc2;   // rc2<0 => never

    // ---- compact survivor keys, rank-sort by (tz, idx), scatter ----
    const unsigned long long mball = __ballot(hit);
    if (lane == 0) scnt[wv] = __popcll(mball);
    __syncthreads();
    int base = 0, L = 0;
    #pragma unroll
    for (int w = 0; w < NCH; ++w) { L += scnt[w]; if (w < wv) base += scnt[w]; }
    if (hit) {
        const int pos = base + __popcll(mball & ((1ull << lane) - 1ull));
        k_tz[pos] = tz;
        k_id[pos] = tid;
    }
    __syncthreads();

    if (hit) {
        int rank = 0;
        for (int j = 0; j < L; ++j) {
            const float kj = k_tz[j];
            rank += (kj < tz || (kj == tz && k_id[j] < tid)) ? 1 : 0;
        }
        smx[rank] = mx;   smy[rank] = my;
        sA[rank]  = g1.x; sB[rank]  = g1.y; sC[rank] = g1.z;
        sop[rank] = g1.w; scr[rank] = g2.x; scg[rank] = g2.y; scb[rank] = g2.z;
    }
    __syncthreads();

    // ---- chunked front-to-back composite over sorted survivors ----
    const int Lc = (L + NCH - 1) / NCH;
    const int k0 = wv * Lc;
    const int k1 = (k0 + Lc < L) ? (k0 + Lc) : L;

    const float fx = (float)(x0 + lane);
    float T = 1.f, ar = 0.f, ag = 0.f, ab = 0.f;

    for (int k = k0; k < k1; ++k) {
        const float dx = fx - smx[k];
        const float dy = fy - smy[k];
        const float power = fmaf(sA[k], dx*dx, fmaf(sB[k], dx*dy, sC[k]*dy*dy));
        if (power > 0.f) continue;
        const float alpha = fminf(0.99f, sop[k] * __expf(power));
        if (alpha < (1.0f / 255.0f)) continue;
        const float w = alpha * T;
        ar = fmaf(w, scr[k], ar);
        ag = fmaf(w, scg[k], ag);
        ab = fmaf(w, scb[k], ab);
        T *= (1.f - alpha);
    }

    pr[wv * SEGW + lane] = ar;
    pg[wv * SEGW + lane] = ag;
    pb[wv * SEGW + lane] = ab;
    pt[wv * SEGW + lane] = T;
    __syncthreads();

    if (tid < SEGW) {
        float Tc = 1.f, rr = 0.f, gg = 0.f, bb = 0.f;
        #pragma unroll
        for (int c2 = 0; c2 < NCH; ++c2) {
            rr = fmaf(Tc, pr[c2 * SEGW + tid], rr);
            gg = fmaf(Tc, pg[c2 * SEGW + tid], gg);
            bb = fmaf(Tc, pb[c2 * SEGW + tid], bb);
            Tc *= pt[c2 * SEGW + tid];
        }
        const int pix = row * IMW + x0 + tid;
        out[pix]          = rr;
        out[65536 + pix]  = gg;
        out[131072 + pix] = bb;
    }
}

extern "C" void kernel_launch(void* const* d_in, const int* in_sizes, int n_in,
                              void* d_out, int out_size, void* d_ws, size_t ws_size,
                              hipStream_t stream) {
    const float* points = (const float*)d_in[0];
    const float* scales = (const float*)d_in[1];
    const float* rots   = (const float*)d_in[2];
    const float* opac   = (const float*)d_in[3];
    const float* shs    = (const float*)d_in[4];
    const float* vm     = (const float*)d_in[5];
    float* out = (float*)d_out;
    float4* gp = (float4*)d_ws;

    gr_prep<<<1, 512, 0, stream>>>(points, scales, rots, opac, shs, vm, gp, out);
    gr_raster<<<IMH * (IMW / SEGW), 512, 0, stream>>>(gp, out);
}

// Round 2
// 70.019 us; speedup vs baseline: 1.0457x; 1.0227x over previous
//
#include <hip/hip_runtime.h>
#include <math.h>

#define PNUM 512
#define IMW 256
#define IMH 256
#define NCH 8      // waves per block (raster)
#define SEGW 64    // pixels per block (one 64-wide row segment)

// Two-kernel pipeline through d_ws (stream-ordered):
//   gr_prep   : 1 block, 512 threads. Full per-gaussian preprocess ONCE.
//               Fast-math rcp/rsq (1-ulp; tolerance is 2^-10) to shorten the
//               latency-bound division chains. Writes 3x float4/gaussian + aux.
//   gr_raster : 1024 blocks (one 64-px row segment). Loads mx/my/rc2/tz (16B),
//               exact-safe cull, ballot-compact, O(L^2) rank-sort by (tz,idx),
//               8-wave chunked front-to-back composite + ordered LDS merge.
//               Param loads (g1,g2) sunk into the hit branch; L==0 early-out;
//               __launch_bounds__(512,8) caps VGPR<=64 so all 1024 blocks run
//               in ONE dispatch round (4 blocks/CU).

__device__ __forceinline__ float frcp(float x) { return __builtin_amdgcn_rcpf(x); }
__device__ __forceinline__ float frsq(float x) { return __builtin_amdgcn_rsqf(x); }

__global__ __launch_bounds__(512) void gr_prep(
    const float* __restrict__ points, const float* __restrict__ scales,
    const float* __restrict__ rots, const float* __restrict__ opac_in,
    const float* __restrict__ shs, const float* __restrict__ vm,
    float4* __restrict__ gp, float* __restrict__ out)
{
    const int i = threadIdx.x;

    const float px = points[3*i], py = points[3*i+1], pz = points[3*i+2];
    const float sx = __expf(scales[3*i]), sy = __expf(scales[3*i+1]), sz = __expf(scales[3*i+2]);
    const float op0 = frcp(1.0f + __expf(-opac_in[i]));
    const float q0 = rots[4*i], q1 = rots[4*i+1], q2 = rots[4*i+2], q3 = rots[4*i+3];
    const float qinv = frsq(q0*q0 + q1*q1 + q2*q2 + q3*q3);
    const float r = q0*qinv, x = q1*qinv, y = q2*qinv, z = q3*qinv;

    const float R00 = 1.f - 2.f*(y*y + z*z);
    const float R01 = 2.f*(x*y - r*z);
    const float R02 = 2.f*(x*z + r*y);
    const float R10 = 2.f*(x*y + r*z);
    const float R11 = 1.f - 2.f*(x*x + z*z);
    const float R12 = 2.f*(y*z - r*x);
    const float R20 = 2.f*(x*z - r*y);
    const float R21 = 2.f*(y*z + r*x);
    const float R22 = 1.f - 2.f*(x*x + y*y);

    const float M00=R00*sx, M01=R01*sy, M02=R02*sz;
    const float M10=R10*sx, M11=R11*sy, M12=R12*sz;
    const float M20=R20*sx, M21=R21*sy, M22=R22*sz;

    const float S00 = M00*M00 + M01*M01 + M02*M02;
    const float S01 = M00*M10 + M01*M11 + M02*M12;
    const float S02 = M00*M20 + M01*M21 + M02*M22;
    const float S11 = M10*M10 + M11*M11 + M12*M12;
    const float S12 = M10*M20 + M11*M21 + M12*M22;
    const float S22 = M20*M20 + M21*M21 + M22*M22;

    const float W00=vm[0], W01=vm[1], W02=vm[2],  T0=vm[3];
    const float W10=vm[4], W11=vm[5], W12=vm[6],  T1=vm[7];
    const float W20=vm[8], W21=vm[9], W22=vm[10], T2=vm[11];
    const float tx = W00*px + W01*py + W02*pz + T0;
    const float ty = W10*px + W11*py + W12*pz + T1;
    const float tz = W20*px + W21*py + W22*pz + T2;

    bool vis = tz > 0.2f;
    const float tzs = vis ? tz : 1.0f;
    const float rtz = frcp(tzs);
    const float lim = 1.3f * 0.5f;
    const float txtz = fminf(fmaxf(tx * rtz, -lim), lim) * tzs;
    const float tytz = fminf(fmaxf(ty * rtz, -lim), lim) * tzs;

    const float FX = 256.0f, FY = 256.0f;
    const float J00 = FX * rtz;
    const float J02 = -FX * txtz * rtz * rtz;
    const float J11 = FY * rtz;
    const float J12 = -FY * tytz * rtz * rtz;

    const float Tm00 = J00*W00 + J02*W20;
    const float Tm01 = J00*W01 + J02*W21;
    const float Tm02 = J00*W02 + J02*W22;
    const float Tm10 = J11*W10 + J12*W20;
    const float Tm11 = J11*W11 + J12*W21;
    const float Tm12 = J11*W12 + J12*W22;

    const float U00 = Tm00*S00 + Tm01*S01 + Tm02*S02;
    const float U01 = Tm00*S01 + Tm01*S11 + Tm02*S12;
    const float U02 = Tm00*S02 + Tm01*S12 + Tm02*S22;
    const float U10 = Tm10*S00 + Tm11*S01 + Tm12*S02;
    const float U11 = Tm10*S01 + Tm11*S11 + Tm12*S12;
    const float U12 = Tm10*S02 + Tm11*S12 + Tm12*S22;

    const float cov00 = U00*Tm00 + U01*Tm01 + U02*Tm02;
    const float cov01 = U00*Tm10 + U01*Tm11 + U02*Tm12;
    const float cov11 = U10*Tm10 + U11*Tm11 + U12*Tm12;

    const float det_orig = cov00*cov11 - cov01*cov01;
    const float a = cov00 + 0.3f, c = cov11 + 0.3f, b = cov01;
    const float det = a*c - b*b;
    vis = vis && (det > 0.f);
    const float dets = (det > 0.f) ? det : 1.0f;
    const float invdet = frcp(dets);
    const float compn = __fsqrt_rn(fmaxf(det_orig * invdet, 0.f));
    const float op = vis ? op0 * compn : 0.f;
    const float A2 = -0.5f * c * invdet;   // -0.5*conA
    const float B2 = b * invdet;           // -conB
    const float C2 = -0.5f * a * invdet;   // -0.5*conC

    const float mid = 0.5f * (a + c);
    const float lam = mid + __fsqrt_rn(fmaxf(mid*mid - det, 0.1f));

    const float mx = FX * tx * rtz + (IMW - 1) * 0.5f;
    const float my = FY * ty * rtz + (IMH - 1) * 0.5f;

    const float SH_C0 = 0.28209479177387814f;
    const float cr = fmaxf(shs[3*i  ] * SH_C0 + 0.5f, 0.f);
    const float cg = fmaxf(shs[3*i+1] * SH_C0 + 0.5f, 0.f);
    const float cb = fmaxf(shs[3*i+2] * SH_C0 + 0.5f, 0.f);

    // alpha >= 1/255 requires |d|^2 <= 2*lam*ln(255*op) (lam >= lambda_max)
    float rc2 = -1.f;
    const float p255 = 255.f * op;
    if (p255 > 1.f) rc2 = 2.f * lam * __logf(p255) * 1.001f + 0.01f;

    gp[i]          = make_float4(mx, my, rc2, tz);
    gp[PNUM + i]   = make_float4(A2, B2, C2, op);
    gp[2*PNUM + i] = make_float4(cr, cg, cb, 0.f);

    // aux outputs
    const float radii = vis ? ceilf(3.f * __fsqrt_rn(lam)) : 0.f;
    out[196608 + 3*i + 0] = 0.f;
    out[196608 + 3*i + 1] = 0.f;
    out[196608 + 3*i + 2] = 0.f;
    out[198144 + i] = radii;
}

__global__ __launch_bounds__(512, 8) void gr_raster(
    const float4* __restrict__ gp, float* __restrict__ out)
{
    __shared__ float k_tz[PNUM];
    __shared__ int   k_id[PNUM];
    __shared__ float smx[PNUM], smy[PNUM], sA[PNUM], sB[PNUM], sC[PNUM];
    __shared__ float sop[PNUM], scr[PNUM], scg[PNUM], scb[PNUM];
    __shared__ float pr[NCH*SEGW], pg[NCH*SEGW], pb[NCH*SEGW], pt[NCH*SEGW];
    __shared__ int scnt[NCH];

    const int tid  = threadIdx.x;      // gaussian id in cull/compact phases
    const int lane = tid & 63;
    const int wv   = tid >> 6;
    const int seg  = blockIdx.x;
    const int row  = seg >> 2;
    const int x0   = (seg & 3) << 6;
    const float fy = (float)row;

    // ---- load cull params only (16 B/thread, L2-resident) ----
    const float4 g0 = gp[tid];            // mx, my, rc2, tz
    const float mx = g0.x, my = g0.y, rc2 = g0.z, tz = g0.w;

    // ---- exact-safe cull vs this segment ----
    const float dxl = (float)x0 - mx;
    const float dxr = mx - (float)(x0 + SEGW - 1);
    const float dxm = fmaxf(0.f, fmaxf(dxl, dxr));
    const float dym = fabsf(fy - my);
    const bool hit = (dxm*dxm + dym*dym) <= rc2;   // rc2<0 => never

    // ---- compact survivor keys ----
    const unsigned long long mball = __ballot(hit);
    if (lane == 0) scnt[wv] = __popcll(mball);
    __syncthreads();
    int base = 0, L = 0;
    #pragma unroll
    for (int w = 0; w < NCH; ++w) { L += scnt[w]; if (w < wv) base += scnt[w]; }

    // ---- empty segment: write zeros and leave (block-uniform, barrier-safe) ----
    if (L == 0) {
        if (tid < SEGW) {
            const int pix = row * IMW + x0 + tid;
            out[pix]          = 0.f;
            out[65536 + pix]  = 0.f;
            out[131072 + pix] = 0.f;
        }
        return;
    }

    if (hit) {
        const int pos = base + __popcll(mball & ((1ull << lane) - 1ull));
        k_tz[pos] = tz;
        k_id[pos] = tid;
    }
    __syncthreads();

    // ---- rank-sort by (tz, idx); scatter params from hit threads only ----
    if (hit) {
        int rank = 0;
        for (int j = 0; j < L; ++j) {
            const float kj = k_tz[j];
            rank += (kj < tz || (kj == tz && k_id[j] < tid)) ? 1 : 0;
        }
        const float4 g1 = gp[PNUM + tid];     // A2, B2, C2, op
        const float4 g2 = gp[2*PNUM + tid];   // cr, cg, cb, -
        smx[rank] = mx;   smy[rank] = my;
        sA[rank]  = g1.x; sB[rank]  = g1.y; sC[rank] = g1.z;
        sop[rank] = g1.w; scr[rank] = g2.x; scg[rank] = g2.y; scb[rank] = g2.z;
    }
    __syncthreads();

    // ---- chunked front-to-back composite over sorted survivors ----
    const int Lc = (L + NCH - 1) / NCH;
    const int k0 = wv * Lc;
    const int k1 = (k0 + Lc < L) ? (k0 + Lc) : L;

    const float fx = (float)(x0 + lane);
    float T = 1.f, ar = 0.f, ag = 0.f, ab = 0.f;

    for (int k = k0; k < k1; ++k) {
        const float dx = fx - smx[k];
        const float dy = fy - smy[k];
        const float power = fmaf(sA[k], dx*dx, fmaf(sB[k], dx*dy, sC[k]*dy*dy));
        if (power > 0.f) continue;
        const float alpha = fminf(0.99f, sop[k] * __expf(power));
        if (alpha < (1.0f / 255.0f)) continue;
        const float w = alpha * T;
        ar = fmaf(w, scr[k], ar);
        ag = fmaf(w, scg[k], ag);
        ab = fmaf(w, scb[k], ab);
        T *= (1.f - alpha);
    }

    pr[wv * SEGW + lane] = ar;
    pg[wv * SEGW + lane] = ag;
    pb[wv * SEGW + lane] = ab;
    pt[wv * SEGW + lane] = T;
    __syncthreads();

    if (tid < SEGW) {
        float Tc = 1.f, rr = 0.f, gg = 0.f, bb = 0.f;
        #pragma unroll
        for (int c2 = 0; c2 < NCH; ++c2) {
            rr = fmaf(Tc, pr[c2 * SEGW + tid], rr);
            gg = fmaf(Tc, pg[c2 * SEGW + tid], gg);
            bb = fmaf(Tc, pb[c2 * SEGW + tid], bb);
            Tc *= pt[c2 * SEGW + tid];
        }
        const int pix = row * IMW + x0 + tid;
        out[pix]          = rr;
        out[65536 + pix]  = gg;
        out[131072 + pix] = bb;
    }
}

extern "C" void kernel_launch(void* const* d_in, const int* in_sizes, int n_in,
                              void* d_out, int out_size, void* d_ws, size_t ws_size,
                              hipStream_t stream) {
    const float* points = (const float*)d_in[0];
    const float* scales = (const float*)d_in[1];
    const float* rots   = (const float*)d_in[2];
    const float* opac   = (const float*)d_in[3];
    const float* shs    = (const float*)d_in[4];
    const float* vm     = (const float*)d_in[5];
    float* out = (float*)d_out;
    float4* gp = (float4*)d_ws;

    gr_prep<<<1, 512, 0, stream>>>(points, scales, rots, opac, shs, vm, gp, out);
    gr_raster<<<IMH * (IMW / SEGW), 512, 0, stream>>>(gp, out);
}